// Round 7
// baseline (470.575 us; speedup 1.0000x reference)
//
#include <hip/hip_runtime.h>

#define Bsz 256
#define Ssz 2048
#define Isz 32
#define Hsz 18
#define SCALE 2.885390081777927f   // 2*log2(e): pre-scales all pre-activations

typedef float f2 __attribute__((ext_vector_type(2)));
typedef float f4 __attribute__((ext_vector_type(4)));

__device__ __forceinline__ float exp2_fast(float x) {
#if __has_builtin(__builtin_amdgcn_exp2f)
    return __builtin_amdgcn_exp2f(x);
#else
    return __expf(x * 0.6931471805599453f);
#endif
}

// K1: xw0T[b][i][t] = SCALE * (sum_k input[b][t][k]*Wih0[i][k] + bih0[i] + bhh0[i])
__global__ __launch_bounds__(256) void input_gemm(
    const float* __restrict__ x,
    const float* __restrict__ Wih0,
    const float* __restrict__ bih0,
    const float* __restrict__ bhh0,
    float* __restrict__ xw0T)
{
    __shared__ float xs[256 * 33];
    int blk = blockIdx.x;                  // 2048 blocks
    int b = blk >> 3;
    int t0 = (blk & 7) << 8;
    int tid = threadIdx.x;

    const float4* src = (const float4*)(x + ((size_t)b * Ssz + t0) * Isz);
#pragma unroll
    for (int k = 0; k < 8; ++k) {
        int l = k * 256 + tid;             // coalesced float4 index
        float4 v = src[l];
        int row = l >> 3, k4 = l & 7;
        float* p = xs + row * 33 + k4 * 4;
        p[0] = v.x; p[1] = v.y; p[2] = v.z; p[3] = v.w;
    }
    __syncthreads();

    float xv[32];
    const float* myrow = xs + tid * 33;
#pragma unroll
    for (int k = 0; k < 32; ++k) xv[k] = myrow[k];

    float* op = xw0T + (size_t)b * (Hsz * Ssz) + (t0 + tid);
#pragma unroll
    for (int ii = 0; ii < Hsz; ++ii) {
        float acc = bih0[ii] + bhh0[ii];
#pragma unroll
        for (int k = 0; k < 32; ++k) acc = fmaf(xv[k], Wih0[ii * Isz + k], acc);
        op[(size_t)ii * Ssz] = acc * SCALE;
    }
}

// K2: pipelined 3-layer scan as a 54-wide recurrence, ONE batch per wave,
// f32 state exchange (16-bit exchange diverges: recurrence amplifies
// per-step error ~500-3000x over 2048 steps — measured round 6).
//
// LDS layout (floats): X[0..17] = 0 forever (g0's prev-window);
// state g at X[18+18g .. 35+18g]. Lane r = 18g+i writes ONE slot X[18+r]
// (64 consecutive words -> 2 lanes/bank, conflict-free). Group g's operand
// window (prev-state 18 || own-state 18) = 36 CONTIGUOUS floats at X[18g],
// read as 18 adjacent float2 loads -> 9x ds_read2_b64 (8B-aligned bases).
// Per-instruction bank spans of the 4 group bases are disjoint -> no
// read conflicts (intra-group same-address reads broadcast).
__global__ __launch_bounds__(64) void rnn_scan(
    const float* __restrict__ xw0T,
    const float* __restrict__ hidden,
    const float* __restrict__ Whh0,
    const float* __restrict__ Wih1, const float* __restrict__ bih1,
    const float* __restrict__ Whh1, const float* __restrict__ bhh1,
    const float* __restrict__ Wih2, const float* __restrict__ bih2,
    const float* __restrict__ Whh2, const float* __restrict__ bhh2,
    float* __restrict__ h2T,
    float* __restrict__ hid_out)
{
    const int b = blockIdx.x;
    const int r = threadIdx.x;
    const int g = (r < 18) ? 0 : (r < 36) ? 1 : (r < 54) ? 2 : 3;
    const int i = r - g * 18;
    const bool lane_active = (g < 3);
    const bool g0lane = (g == 0);
    const bool g2lane = (g == 2);

    __shared__ __align__(16) float X[96];
    for (int k = r; k < 96; k += 64) X[k] = 0.0f;
    __builtin_amdgcn_wave_barrier();

    // Per-lane weight row: w[0..17] = Wih (applies to prev-group state),
    // w[18..35] = Whh (own state). Pre-scaled by SCALE.
    float w[36];
    float econst = 0.0f;
    float h = 0.0f;
    if (lane_active) {
        const float* Whh = (g == 0) ? Whh0 : (g == 1) ? Whh1 : Whh2;
#pragma unroll
        for (int j = 0; j < Hsz; ++j) w[18 + j] = Whh[i * Hsz + j] * SCALE;
        if (g >= 1) {
            const float* Wih = (g == 1) ? Wih1 : Wih2;
            const float* bi  = (g == 1) ? bih1 : bih2;
            const float* bh  = (g == 1) ? bhh1 : bhh2;
#pragma unroll
            for (int j = 0; j < Hsz; ++j) w[j] = Wih[i * Hsz + j] * SCALE;
            econst = (bi[i] + bh[i]) * SCALE;
        } else {
#pragma unroll
            for (int j = 0; j < Hsz; ++j) w[j] = 0.0f;   // g0: prev-window is zeros
        }
        h = hidden[(g * Bsz + b) * Hsz + i];
    } else {
#pragma unroll
        for (int j = 0; j < 36; ++j) w[j] = 0.0f;
    }

    f2 w2[18];
#pragma unroll
    for (int k = 0; k < 18; ++k) w2[k] = f2{w[2 * k], w[2 * k + 1]};

    const int ws = 18 + r;                       // own write slot
    const f2* xw2r = (const f2*)(X + 18 * g);    // 36-float window, 18 f2 loads

    X[ws] = h;
    __builtin_amdgcn_wave_barrier();

    const float* xwp = xw0T + (size_t)b * (Hsz * Ssz) + (size_t)((g == 0) ? i : 0) * Ssz;
    float*       hop2 = h2T + (size_t)b * (Hsz * Ssz) + (size_t)i * Ssz; // g2 only

    f4 cur = *(const f4*)(xwp + 0);
    f4 nxt = *(const f4*)(xwp + 4);
    f4 ob;  // g2 output quad; slot for t is ob[t&3]

    // One tick: 18 f2 reads (merged to 9x ds_read2_b64) -> 18 pk_fma in 3
    // chains -> reduce -> tanh. e folded into chain-0 init.
    auto do_tick = [&](float e, bool dostore, int st) -> float {
        f2 d0  = xw2r[0],  d1  = xw2r[1],  d2  = xw2r[2],  d3  = xw2r[3];
        f2 d4  = xw2r[4],  d5  = xw2r[5],  d6  = xw2r[6],  d7  = xw2r[7];
        f2 d8  = xw2r[8],  d9  = xw2r[9],  d10 = xw2r[10], d11 = xw2r[11];
        f2 d12 = xw2r[12], d13 = xw2r[13], d14 = xw2r[14], d15 = xw2r[15];
        f2 d16 = xw2r[16], d17 = xw2r[17];
        if (dostore && g2lane) *(f4*)(hop2 + st) = ob;   // off the dep chain
        f2 a0 = f2{e, 0.0f}, a1 = f2{0.0f, 0.0f}, a2 = f2{0.0f, 0.0f};
        a0 = __builtin_elementwise_fma(w2[0],  d0,  a0);
        a1 = __builtin_elementwise_fma(w2[1],  d1,  a1);
        a2 = __builtin_elementwise_fma(w2[2],  d2,  a2);
        a0 = __builtin_elementwise_fma(w2[3],  d3,  a0);
        a1 = __builtin_elementwise_fma(w2[4],  d4,  a1);
        a2 = __builtin_elementwise_fma(w2[5],  d5,  a2);
        a0 = __builtin_elementwise_fma(w2[6],  d6,  a0);
        a1 = __builtin_elementwise_fma(w2[7],  d7,  a1);
        a2 = __builtin_elementwise_fma(w2[8],  d8,  a2);
        a0 = __builtin_elementwise_fma(w2[9],  d9,  a0);
        a1 = __builtin_elementwise_fma(w2[10], d10, a1);
        a2 = __builtin_elementwise_fma(w2[11], d11, a2);
        a0 = __builtin_elementwise_fma(w2[12], d12, a0);
        a1 = __builtin_elementwise_fma(w2[13], d13, a1);
        a2 = __builtin_elementwise_fma(w2[14], d14, a2);
        a0 = __builtin_elementwise_fma(w2[15], d15, a0);
        a1 = __builtin_elementwise_fma(w2[16], d16, a1);
        a2 = __builtin_elementwise_fma(w2[17], d17, a2);
        f2 s = (a0 + a1) + a2;
        float a = s.x + s.y;
        float t = exp2_fast(a);
        return fmaf(-2.0f, __builtin_amdgcn_rcpf(t + 1.0f), 1.0f);
    };

    // ---- prologue: T = 0..3, masked updates, no store ----
    {
        f4 fut = *(const f4*)(xwp + 8);
        float ev[4] = {cur.x, cur.y, cur.z, cur.w};
#pragma unroll
        for (int u = 0; u < 4; ++u) {
            const int T = u;
            float e = g0lane ? ev[u] : econst;
            float nh = do_tick(e, false, 0);
            bool upd = lane_active && (T >= g);
            h = upd ? nh : h;
            X[ws] = h;
            if (u == 2) ob.x = h; else if (u == 3) ob.y = h;
            __builtin_amdgcn_wave_barrier();
        }
        cur = nxt; nxt = fut;
    }

    // ---- interior: T = 4..2047, unmasked; g2 flushes quad (tb-4..tb-1) at u==2 ----
    for (int tb = 4; tb < Ssz; tb += 4) {
        int tl = tb + 8; if (tl > Ssz - 4) tl = Ssz - 4;
        f4 fut = *(const f4*)(xwp + tl);
        float ev[4] = {cur.x, cur.y, cur.z, cur.w};
#pragma unroll
        for (int u = 0; u < 4; ++u) {
            float e = g0lane ? ev[u] : econst;
            h = do_tick(e, u == 2, tb - 4);   // idle lanes: tanh(0)=0, harmless
            X[ws] = h;
            if (u == 0) ob.z = h;
            else if (u == 1) ob.w = h;
            else if (u == 2) ob.x = h;
            else ob.y = h;
            __builtin_amdgcn_wave_barrier();
        }
        cur = nxt; nxt = fut;
    }

    // ---- tail: T = 2048..2049, masked (freeze finished groups) ----
    {
        float ev[2] = {cur.x, cur.y};
#pragma unroll
        for (int u = 0; u < 2; ++u) {
            const int T = Ssz + u;
            float e = g0lane ? ev[u] : econst;
            float nh = do_tick(e, false, 0);
            bool upd = lane_active && (T <= Ssz - 1 + g);
            h = upd ? nh : h;
            X[ws] = h;
            if (u == 0) ob.z = h; else ob.w = h;
            __builtin_amdgcn_wave_barrier();
        }
        if (g2lane) *(f4*)(hop2 + Ssz - 4) = ob;  // final quad t=2044..2047
    }

    if (lane_active) hid_out[(g * Bsz + b) * Hsz + i] = h;
}

// K3: MLP head 18->18->10->8->4->2->1, one thread per (b,t).
__global__ __launch_bounds__(256) void mlp_head(
    const float* __restrict__ h2T,
    const float* __restrict__ W1, const float* __restrict__ b1,
    const float* __restrict__ W2, const float* __restrict__ b2,
    const float* __restrict__ W3, const float* __restrict__ b3,
    const float* __restrict__ W4, const float* __restrict__ b4,
    const float* __restrict__ W5, const float* __restrict__ b5,
    const float* __restrict__ W6, const float* __restrict__ b6,
    float* __restrict__ out)
{
    int idx = blockIdx.x * 256 + threadIdx.x;  // = b*S + t
    int b = idx >> 11;
    int t = idx & (Ssz - 1);
    const float* hp = h2T + (size_t)b * (Hsz * Ssz) + t;
    float v[Hsz];
#pragma unroll
    for (int j = 0; j < Hsz; ++j) v[j] = hp[(size_t)j * Ssz];

    float a1[18];
#pragma unroll
    for (int o = 0; o < 18; ++o) {
        float acc = b1[o];
#pragma unroll
        for (int j = 0; j < 18; ++j) acc = fmaf(W1[o * 18 + j], v[j], acc);
        a1[o] = fmaxf(acc, 0.0f);
    }
    float a2[10];
#pragma unroll
    for (int o = 0; o < 10; ++o) {
        float acc = b2[o];
#pragma unroll
        for (int j = 0; j < 18; ++j) acc = fmaf(W2[o * 18 + j], a1[j], acc);
        a2[o] = fmaxf(acc, 0.0f);
    }
    float a3[8];
#pragma unroll
    for (int o = 0; o < 8; ++o) {
        float acc = b3[o];
#pragma unroll
        for (int j = 0; j < 10; ++j) acc = fmaf(W3[o * 10 + j], a2[j], acc);
        a3[o] = fmaxf(acc, 0.0f);
    }
    float a4[4];
#pragma unroll
    for (int o = 0; o < 4; ++o) {
        float acc = b4[o];
#pragma unroll
        for (int j = 0; j < 8; ++j) acc = fmaf(W4[o * 8 + j], a3[j], acc);
        a4[o] = fmaxf(acc, 0.0f);
    }
    float a5[2];
#pragma unroll
    for (int o = 0; o < 2; ++o) {
        float acc = b5[o];
#pragma unroll
        for (int j = 0; j < 4; ++j) acc = fmaf(W5[o * 4 + j], a4[j], acc);
        a5[o] = fmaxf(acc, 0.0f);
    }
    float r6 = b6[0];
    r6 = fmaf(W6[0], a5[0], r6);
    r6 = fmaf(W6[1], a5[1], r6);
    out[idx] = r6;
}

extern "C" void kernel_launch(void* const* d_in, const int* in_sizes, int n_in,
                              void* d_out, int out_size, void* d_ws, size_t ws_size,
                              hipStream_t stream) {
    (void)in_sizes; (void)n_in; (void)out_size; (void)ws_size;
    const float* input  = (const float*)d_in[0];
    const float* hidden = (const float*)d_in[1];
    const float* Wih0 = (const float*)d_in[2];  const float* bih0 = (const float*)d_in[3];
    const float* Whh0 = (const float*)d_in[4];  const float* bhh0 = (const float*)d_in[5];
    const float* Wih1 = (const float*)d_in[6];  const float* bih1 = (const float*)d_in[7];
    const float* Whh1 = (const float*)d_in[8];  const float* bhh1 = (const float*)d_in[9];
    const float* Wih2 = (const float*)d_in[10]; const float* bih2 = (const float*)d_in[11];
    const float* Whh2 = (const float*)d_in[12]; const float* bhh2 = (const float*)d_in[13];
    const float* W1 = (const float*)d_in[14]; const float* b1 = (const float*)d_in[15];
    const float* W2 = (const float*)d_in[16]; const float* b2 = (const float*)d_in[17];
    const float* W3 = (const float*)d_in[18]; const float* b3 = (const float*)d_in[19];
    const float* W4 = (const float*)d_in[20]; const float* b4 = (const float*)d_in[21];
    const float* W5 = (const float*)d_in[22]; const float* b5 = (const float*)d_in[23];
    const float* W6 = (const float*)d_in[24]; const float* b6 = (const float*)d_in[25];

    float* xw0T = (float*)d_ws;                         // [B][18][S]
    float* h2T  = xw0T + (size_t)Bsz * Hsz * Ssz;       // [B][18][S]
    float* out  = (float*)d_out;                        // [B*S]
    float* hout = out + (size_t)Bsz * Ssz;              // [3][B][18]

    input_gemm<<<dim3(2048), dim3(256), 0, stream>>>(input, Wih0, bih0, bhh0, xw0T);
    rnn_scan<<<dim3(256), dim3(64), 0, stream>>>(xw0T, hidden, Whh0,
                                                 Wih1, bih1, Whh1, bhh1,
                                                 Wih2, bih2, Whh2, bhh2,
                                                 h2T, hout);
    mlp_head<<<dim3(2048), dim3(256), 0, stream>>>(h2T, W1, b1, W2, b2, W3, b3,
                                                   W4, b4, W5, b5, W6, b6, out);
}

// Round 8
// 457.959 us; speedup vs baseline: 1.0275x; 1.0275x over previous
//
#include <hip/hip_runtime.h>

#define Bsz 256
#define Ssz 2048
#define Isz 32
#define Hsz 18
#define SCALE 2.885390081777927f   // 2*log2(e): pre-scales all pre-activations

typedef float f2 __attribute__((ext_vector_type(2)));
typedef float f4 __attribute__((ext_vector_type(4)));

#define LO2(v) __builtin_shufflevector(v, v, 0, 1)
#define HI2(v) __builtin_shufflevector(v, v, 2, 3)

__device__ __forceinline__ float exp2_fast(float x) {
#if __has_builtin(__builtin_amdgcn_exp2f)
    return __builtin_amdgcn_exp2f(x);
#else
    return __expf(x * 0.6931471805599453f);
#endif
}

// K1: xw0T[b][i][t] = SCALE * (sum_k input[b][t][k]*Wih0[i][k] + bih0[i] + bhh0[i])
__global__ __launch_bounds__(256) void input_gemm(
    const float* __restrict__ x,
    const float* __restrict__ Wih0,
    const float* __restrict__ bih0,
    const float* __restrict__ bhh0,
    float* __restrict__ xw0T)
{
    __shared__ float xs[256 * 33];
    int blk = blockIdx.x;                  // 2048 blocks
    int b = blk >> 3;
    int t0 = (blk & 7) << 8;
    int tid = threadIdx.x;

    const float4* src = (const float4*)(x + ((size_t)b * Ssz + t0) * Isz);
#pragma unroll
    for (int k = 0; k < 8; ++k) {
        int l = k * 256 + tid;             // coalesced float4 index
        float4 v = src[l];
        int row = l >> 3, k4 = l & 7;
        float* p = xs + row * 33 + k4 * 4;
        p[0] = v.x; p[1] = v.y; p[2] = v.z; p[3] = v.w;
    }
    __syncthreads();

    float xv[32];
    const float* myrow = xs + tid * 33;
#pragma unroll
    for (int k = 0; k < 32; ++k) xv[k] = myrow[k];

    float* op = xw0T + (size_t)b * (Hsz * Ssz) + (t0 + tid);
#pragma unroll
    for (int ii = 0; ii < Hsz; ++ii) {
        float acc = bih0[ii] + bhh0[ii];
#pragma unroll
        for (int k = 0; k < 32; ++k) acc = fmaf(xv[k], Wih0[ii * Isz + k], acc);
        op[(size_t)ii * Ssz] = acc * SCALE;
    }
}

// K2: 3-layer scan, ONE batch/wave, f32 exchange (16-bit diverges — round 6),
// with L=2 pipeline lag: group g at tick T computes t = T - 2g.
// The prev-layer feed needed at tick T+1 was written at end of T-1, so its
// 5 LDS reads issue at tick T (before tick T's write; in-order DS pipe per
// wave guarantees the old value) and its dot folds into register xp
// OFF-CHAIN. Critical chain/tick: write -> 5 own reads -> dot -> tanh.
//
// LDS layout (floats, stride 20 = 80B so every window base is 16B-aligned):
//   X[0..17] = 0 forever (g0's x-window); state g at X[20(g+1) .. +17].
// Lane r=18g+i writes one slot X[20(g+1)+i]. All 5 read offsets x 4 group
// bases are bank-disjoint (verified); writes <=3 lanes/bank (~free).
__global__ __launch_bounds__(64) void rnn_scan(
    const float* __restrict__ xw0T,
    const float* __restrict__ hidden,
    const float* __restrict__ Whh0,
    const float* __restrict__ Wih1, const float* __restrict__ bih1,
    const float* __restrict__ Whh1, const float* __restrict__ bhh1,
    const float* __restrict__ Wih2, const float* __restrict__ bih2,
    const float* __restrict__ Whh2, const float* __restrict__ bhh2,
    float* __restrict__ h2T,
    float* __restrict__ hid_out)
{
    const int b = blockIdx.x;
    const int r = threadIdx.x;
    const int g = (r < 18) ? 0 : (r < 36) ? 1 : (r < 54) ? 2 : 3;
    const int i = r - g * 18;
    const bool lane_active = (g < 3);
    const bool g0lane = (g == 0);
    const bool g2lane = (g == 2);

    __shared__ __align__(16) float X[112];
    for (int k = r; k < 112; k += 64) X[k] = 0.0f;
    __builtin_amdgcn_wave_barrier();

    // w[0..17] = Wih row (applies to prev-group state), w[18..35] = Whh row.
    float w[36];
    float econst = 0.0f;
    float h = 0.0f;
    if (lane_active) {
        const float* Whh = (g == 0) ? Whh0 : (g == 1) ? Whh1 : Whh2;
#pragma unroll
        for (int j = 0; j < Hsz; ++j) w[18 + j] = Whh[i * Hsz + j] * SCALE;
        if (g >= 1) {
            const float* Wih = (g == 1) ? Wih1 : Wih2;
            const float* bi  = (g == 1) ? bih1 : bih2;
            const float* bh  = (g == 1) ? bhh1 : bhh2;
#pragma unroll
            for (int j = 0; j < Hsz; ++j) w[j] = Wih[i * Hsz + j] * SCALE;
            econst = (bi[i] + bh[i]) * SCALE;
        } else {
#pragma unroll
            for (int j = 0; j < Hsz; ++j) w[j] = 0.0f;   // g0: x-window is zeros
        }
        h = hidden[(g * Bsz + b) * Hsz + i];
    } else {
#pragma unroll
        for (int j = 0; j < 36; ++j) w[j] = 0.0f;
    }

    f4 wx4[4], wh4[4];
    f2 wxt, wht;
#pragma unroll
    for (int k = 0; k < 4; ++k) {
        wx4[k] = f4{w[4*k], w[4*k+1], w[4*k+2], w[4*k+3]};
        wh4[k] = f4{w[18+4*k], w[18+4*k+1], w[18+4*k+2], w[18+4*k+3]};
    }
    wxt = f2{w[16], w[17]};
    wht = f2{w[34], w[35]};

    const int ws = 20 * (g + 1) + i;                 // own write slot
    const f4* ro4 = (const f4*)(X + 20 * (g + 1));   // own-state window
    const f2* ro2 = (const f2*)(X + 20 * (g + 1) + 16);
    const f4* rx4 = (const f4*)(X + 20 * g);         // prev-state window
    const f2* rx2 = (const f2*)(X + 20 * g + 16);

    X[ws] = h;
    __builtin_amdgcn_wave_barrier();

    const float* xwp = xw0T + (size_t)b * (Hsz * Ssz) + (size_t)((g == 0) ? i : 0) * Ssz;
    float*       hop2 = h2T + (size_t)b * (Hsz * Ssz) + (size_t)i * Ssz; // g2 only

    f4 cur = *(const f4*)(xwp + 0);
    f4 nxt = *(const f4*)(xwp + 4);
    f4 ob;      // g2 output quad; slot for t is t&3 (== tick&3 since lag 4)
    f2 xp;      // prev-layer partial (+ e) for the CURRENT tick, from last tick

    // pre-loop: xp for tick 0 (x-window holds initial states; e(0) = cur.x)
    {
        f4 x0 = rx4[0], x1 = rx4[1], x2 = rx4[2], x3 = rx4[3];
        f2 x4 = rx2[0];
        float e0 = g0lane ? cur.x : econst;
        f4 p0 = __builtin_elementwise_fma(wx4[0], x0, f4{e0, 0.0f, 0.0f, 0.0f});
        f4 p1 = __builtin_elementwise_fma(wx4[1], x1, f4{0.0f, 0.0f, 0.0f, 0.0f});
        p0 = __builtin_elementwise_fma(wx4[2], x2, p0);
        p1 = __builtin_elementwise_fma(wx4[3], x3, p1);
        f2 pt = __builtin_elementwise_fma(wxt, x4, f2{0.0f, 0.0f});
        f4 q = p0 + p1;
        xp = (LO2(q) + HI2(q)) + pt;
    }

    // One tick. e_next folds into NEXT tick's xp. In-order DS pipe: x-reads
    // issued before this tick's write correctly see the T-1 value.
    auto tick = [&](float e_next, bool use_mask, bool upd, bool dostore, int st) {
        f4 o0 = ro4[0], o1 = ro4[1], o2 = ro4[2], o3 = ro4[3];   // on-chain
        f2 o4 = ro2[0];
        f4 x0 = rx4[0], x1 = rx4[1], x2 = rx4[2], x3 = rx4[3];   // for T+1
        f2 x4 = rx2[0];
        if (dostore && g2lane) *(f4*)(hop2 + st) = ob;           // off-chain
        // own-state dot (on-chain) + xp combine
        f4 a0 = __builtin_elementwise_fma(wh4[0], o0, f4{0.0f, 0.0f, 0.0f, 0.0f});
        f4 a1 = __builtin_elementwise_fma(wh4[1], o1, f4{0.0f, 0.0f, 0.0f, 0.0f});
        a0 = __builtin_elementwise_fma(wh4[2], o2, a0);
        a1 = __builtin_elementwise_fma(wh4[3], o3, a1);
        f2 at = __builtin_elementwise_fma(wht, o4, xp);
        f4 s4 = a0 + a1;
        f2 s2 = (LO2(s4) + HI2(s4)) + at;
        float a = s2.x + s2.y;
        float t = exp2_fast(a);
        float nh = fmaf(-2.0f, __builtin_amdgcn_rcpf(t + 1.0f), 1.0f);
        h = use_mask ? (upd ? nh : h) : nh;
        X[ws] = h;
        // next tick's prev-layer partial (off-chain)
        f4 p0 = __builtin_elementwise_fma(wx4[0], x0, f4{e_next, 0.0f, 0.0f, 0.0f});
        f4 p1 = __builtin_elementwise_fma(wx4[1], x1, f4{0.0f, 0.0f, 0.0f, 0.0f});
        p0 = __builtin_elementwise_fma(wx4[2], x2, p0);
        p1 = __builtin_elementwise_fma(wx4[3], x3, p1);
        f2 pt = __builtin_elementwise_fma(wxt, x4, f2{0.0f, 0.0f});
        f4 q = p0 + p1;
        xp = (LO2(q) + HI2(q)) + pt;
        __builtin_amdgcn_wave_barrier();
    };

    // ---- prologue: T = 0..3, masked (upd iff T >= 2g), no ob/store ----
    {
        f4 fut = *(const f4*)(xwp + 8);
        float en[4] = {cur.y, cur.z, cur.w, nxt.x};   // e(T+1)
#pragma unroll
        for (int u = 0; u < 4; ++u) {
            const int T = u;
            float e_next = g0lane ? en[u] : econst;
            bool upd = lane_active && (T >= 2 * g);
            tick(e_next, true, upd, false, 0);
        }
        cur = nxt; nxt = fut;
    }

    // ---- interior: T = 4..2047 unmasked; g2 t = T-4; flush quad at u==0 ----
    for (int tb = 4; tb < Ssz; tb += 4) {
        int tl = tb + 8; if (tl > Ssz - 4) tl = Ssz - 4;
        f4 fut = *(const f4*)(xwp + tl);
        float en[4] = {cur.y, cur.z, cur.w, nxt.x};
#pragma unroll
        for (int u = 0; u < 4; ++u) {
            float e_next = g0lane ? en[u] : econst;
            tick(e_next, false, false, (u == 0) && (tb >= 8), tb - 8);
            if (u == 0) ob.x = h;
            else if (u == 1) ob.y = h;
            else if (u == 2) ob.z = h;
            else ob.w = h;
        }
        cur = nxt; nxt = fut;
    }

    // ---- tail: T = 2048..2051, masked (upd iff T <= 2047 + 2g) ----
    {
        float en[4] = {cur.y, cur.z, cur.w, cur.w};   // g0 frozen; value unused
#pragma unroll
        for (int u = 0; u < 4; ++u) {
            const int T = Ssz + u;
            float e_next = g0lane ? en[u] : econst;
            bool upd = lane_active && (T <= Ssz - 1 + 2 * g);
            tick(e_next, true, upd, (u == 0), Ssz - 8);
            if (u == 0) ob.x = h;
            else if (u == 1) ob.y = h;
            else if (u == 2) ob.z = h;
            else ob.w = h;
        }
        if (g2lane) *(f4*)(hop2 + Ssz - 4) = ob;  // final quad t=2044..2047
    }

    if (lane_active) hid_out[(g * Bsz + b) * Hsz + i] = h;
}

// K3: MLP head 18->18->10->8->4->2->1, one thread per (b,t).
__global__ __launch_bounds__(256) void mlp_head(
    const float* __restrict__ h2T,
    const float* __restrict__ W1, const float* __restrict__ b1,
    const float* __restrict__ W2, const float* __restrict__ b2,
    const float* __restrict__ W3, const float* __restrict__ b3,
    const float* __restrict__ W4, const float* __restrict__ b4,
    const float* __restrict__ W5, const float* __restrict__ b5,
    const float* __restrict__ W6, const float* __restrict__ b6,
    float* __restrict__ out)
{
    int idx = blockIdx.x * 256 + threadIdx.x;  // = b*S + t
    int b = idx >> 11;
    int t = idx & (Ssz - 1);
    const float* hp = h2T + (size_t)b * (Hsz * Ssz) + t;
    float v[Hsz];
#pragma unroll
    for (int j = 0; j < Hsz; ++j) v[j] = hp[(size_t)j * Ssz];

    float a1[18];
#pragma unroll
    for (int o = 0; o < 18; ++o) {
        float acc = b1[o];
#pragma unroll
        for (int j = 0; j < 18; ++j) acc = fmaf(W1[o * 18 + j], v[j], acc);
        a1[o] = fmaxf(acc, 0.0f);
    }
    float a2[10];
#pragma unroll
    for (int o = 0; o < 10; ++o) {
        float acc = b2[o];
#pragma unroll
        for (int j = 0; j < 18; ++j) acc = fmaf(W2[o * 18 + j], a1[j], acc);
        a2[o] = fmaxf(acc, 0.0f);
    }
    float a3[8];
#pragma unroll
    for (int o = 0; o < 8; ++o) {
        float acc = b3[o];
#pragma unroll
        for (int j = 0; j < 10; ++j) acc = fmaf(W3[o * 10 + j], a2[j], acc);
        a3[o] = fmaxf(acc, 0.0f);
    }
    float a4[4];
#pragma unroll
    for (int o = 0; o < 4; ++o) {
        float acc = b4[o];
#pragma unroll
        for (int j = 0; j < 8; ++j) acc = fmaf(W4[o * 8 + j], a3[j], acc);
        a4[o] = fmaxf(acc, 0.0f);
    }
    float a5[2];
#pragma unroll
    for (int o = 0; o < 2; ++o) {
        float acc = b5[o];
#pragma unroll
        for (int j = 0; j < 4; ++j) acc = fmaf(W5[o * 4 + j], a4[j], acc);
        a5[o] = fmaxf(acc, 0.0f);
    }
    float r6 = b6[0];
    r6 = fmaf(W6[0], a5[0], r6);
    r6 = fmaf(W6[1], a5[1], r6);
    out[idx] = r6;
}

extern "C" void kernel_launch(void* const* d_in, const int* in_sizes, int n_in,
                              void* d_out, int out_size, void* d_ws, size_t ws_size,
                              hipStream_t stream) {
    (void)in_sizes; (void)n_in; (void)out_size; (void)ws_size;
    const float* input  = (const float*)d_in[0];
    const float* hidden = (const float*)d_in[1];
    const float* Wih0 = (const float*)d_in[2];  const float* bih0 = (const float*)d_in[3];
    const float* Whh0 = (const float*)d_in[4];  const float* bhh0 = (const float*)d_in[5];
    const float* Wih1 = (const float*)d_in[6];  const float* bih1 = (const float*)d_in[7];
    const float* Whh1 = (const float*)d_in[8];  const float* bhh1 = (const float*)d_in[9];
    const float* Wih2 = (const float*)d_in[10]; const float* bih2 = (const float*)d_in[11];
    const float* Whh2 = (const float*)d_in[12]; const float* bhh2 = (const float*)d_in[13];
    const float* W1 = (const float*)d_in[14]; const float* b1 = (const float*)d_in[15];
    const float* W2 = (const float*)d_in[16]; const float* b2 = (const float*)d_in[17];
    const float* W3 = (const float*)d_in[18]; const float* b3 = (const float*)d_in[19];
    const float* W4 = (const float*)d_in[20]; const float* b4 = (const float*)d_in[21];
    const float* W5 = (const float*)d_in[22]; const float* b5 = (const float*)d_in[23];
    const float* W6 = (const float*)d_in[24]; const float* b6 = (const float*)d_in[25];

    float* xw0T = (float*)d_ws;                         // [B][18][S]
    float* h2T  = xw0T + (size_t)Bsz * Hsz * Ssz;       // [B][18][S]
    float* out  = (float*)d_out;                        // [B*S]
    float* hout = out + (size_t)Bsz * Ssz;              // [3][B][18]

    input_gemm<<<dim3(2048), dim3(256), 0, stream>>>(input, Wih0, bih0, bhh0, xw0T);
    rnn_scan<<<dim3(256), dim3(64), 0, stream>>>(xw0T, hidden, Whh0,
                                                 Wih1, bih1, Whh1, bhh1,
                                                 Wih2, bih2, Whh2, bhh2,
                                                 h2T, hout);
    mlp_head<<<dim3(2048), dim3(256), 0, stream>>>(h2T, W1, b1, W2, b2, W3, b3,
                                                   W4, b4, W5, b5, W6, b6, out);
}